// Round 7
// baseline (1732.617 us; speedup 1.0000x reference)
//
#include <hip/hip_runtime.h>
#include <math.h>

// Problem constants
#define Bn   8
#define Sn   1024
#define Dn   512
#define Hn   8
#define DKn  64
#define Ln   6
#define DFFn 2048
#define Mn   (Bn * Sn)   // 8192 rows

typedef __bf16 bf16x8 __attribute__((ext_vector_type(8)));
typedef __bf16 bf16x4 __attribute__((ext_vector_type(4)));
typedef float  f32x4  __attribute__((ext_vector_type(4)));

// async global->LDS, 16B per lane. LDS dest must be wave-uniform base + lane*16.
__device__ __forceinline__ void gl_lds16(const void* g, void* l) {
    __builtin_amdgcn_global_load_lds(
        (const __attribute__((address_space(1))) void*)g,
        (__attribute__((address_space(3))) void*)l, 16, 0, 0);
}

// ---------------------------------------------------------------------------
// fp32 -> bf16 cast
// ---------------------------------------------------------------------------
__global__ __launch_bounds__(256) void k_cast_bf16(const float* __restrict__ in,
                                                   __bf16* __restrict__ out, int n) {
    int i = blockIdx.x * 256 + threadIdx.x;
    if (i < n) out[i] = (__bf16)in[i];
}

// ---------------------------------------------------------------------------
// All 4 weight matrices of one layer: W[K][N] fp32 -> Wt[N][K] bf16.
// 32x32 tiles, 32x8 threads. Tile ranges: Wq 768 | Wo 256 | W1 1024 | W2 1024.
// ---------------------------------------------------------------------------
__global__ __launch_bounds__(256) void k_trans_all(
    const float* __restrict__ qkv_w, const float* __restrict__ out_w,
    const float* __restrict__ w1, const float* __restrict__ w2,
    __bf16* __restrict__ Wq, __bf16* __restrict__ Wo,
    __bf16* __restrict__ W1o, __bf16* __restrict__ W2o)
{
    const int t = blockIdx.x;
    const float* src; __bf16* dst; int K, N, n0, k0;
    if (t < 768)       { src = qkv_w; dst = Wq;  K = 512;  N = 1536; int u = t;        n0 = (u % 48) * 32; k0 = (u / 48) * 32; }
    else if (t < 1024) { src = out_w; dst = Wo;  K = 512;  N = 512;  int u = t - 768;  n0 = (u % 16) * 32; k0 = (u / 16) * 32; }
    else if (t < 2048) { src = w1;    dst = W1o; K = 512;  N = 2048; int u = t - 1024; n0 = (u % 64) * 32; k0 = (u / 64) * 32; }
    else               { src = w2;    dst = W2o; K = 2048; N = 512;  int u = t - 2048; n0 = (u % 16) * 32; k0 = (u / 16) * 32; }

    __shared__ float tt[32][33];
    const int tx = threadIdx.x, ty = threadIdx.y;
    #pragma unroll
    for (int r = 0; r < 4; r++)
        tt[ty + 8 * r][tx] = src[(size_t)(k0 + ty + 8 * r) * N + n0 + tx];
    __syncthreads();
    #pragma unroll
    for (int r = 0; r < 4; r++)
        dst[(size_t)(n0 + ty + 8 * r) * K + k0 + tx] = (__bf16)tt[tx][ty + 8 * r];
}

// ---------------------------------------------------------------------------
// MFMA GEMM: C[M,N] = act(A[M,K]bf16 @ Bt[N,K]bf16^T + bias[N]fp32)
// Block: 256 thr = 4 waves (2x2). Tile: 128 x (JT*32). BK=32 (m97-verified;
// BK=64 regressed — m132-style occupancy/amortization loss on short K-loops).
// A/B fragment: elem[j] = X[lane&15][ (lane>>4)*8 + j ]  (m97-verified)
// C/D: col = lane&15, row = (lane>>4)*4 + reg            (m89/m91-verified)
// VW=1 (QKV only): cols >=1024 are V -> also scatter into Vt[b*8+h][d][s].
// ---------------------------------------------------------------------------
template <int RELU, int OUTBF, int JT, int VW>
__global__ __launch_bounds__(256) void k_gemm_mfma(
    const __bf16* __restrict__ A, const __bf16* __restrict__ Bt,
    const float* __restrict__ bias, void* __restrict__ Cout,
    __bf16* __restrict__ Vt, int M, int N, int K)
{
    constexpr int BN = JT * 32;   // 128 or 64
    __shared__ __bf16 As[128][32];
    __shared__ __bf16 Bs[BN][32];
    const int tid  = threadIdx.x;
    const int lane = tid & 63;
    const int wave = tid >> 6;
    const int wy   = wave >> 1, wx = wave & 1;
    const int m16  = lane & 15, quad = lane >> 4;
    const int bm   = blockIdx.y * 128, bn = blockIdx.x * BN;

    f32x4 acc[4][JT];
    #pragma unroll
    for (int i = 0; i < 4; i++)
        #pragma unroll
        for (int j = 0; j < JT; j++)
            acc[i][j] = (f32x4){0.f, 0.f, 0.f, 0.f};

    const __bf16* Ap = A  + (size_t)bm * K;
    const __bf16* Bp = Bt + (size_t)bn * K;

    for (int k0 = 0; k0 < K; k0 += 32) {
        __syncthreads();
        #pragma unroll
        for (int c = 0; c < 2; c++) {           // A: 128x32 bf16 = 512 x 16B
            int lin = tid + c * 256;
            int row = lin >> 2, kc = (lin & 3) << 3;
            gl_lds16(Ap + (size_t)row * K + k0 + kc, (void*)(&As[0][0] + lin * 8));
        }
        #pragma unroll
        for (int c = 0; c < JT / 2; c++) {      // B: BNx32 bf16
            int lin = tid + c * 256;
            int row = lin >> 2, kc = (lin & 3) << 3;
            gl_lds16(Bp + (size_t)row * K + k0 + kc, (void*)(&Bs[0][0] + lin * 8));
        }
        __syncthreads();

        bf16x8 af[4], bfr[JT];
        #pragma unroll
        for (int i = 0; i < 4; i++)
            af[i] = *(const bf16x8*)&As[wy * 64 + i * 16 + m16][quad * 8];
        #pragma unroll
        for (int j = 0; j < JT; j++)
            bfr[j] = *(const bf16x8*)&Bs[wx * JT * 16 + j * 16 + m16][quad * 8];
        #pragma unroll
        for (int i = 0; i < 4; i++)
            #pragma unroll
            for (int j = 0; j < JT; j++)
                acc[i][j] = __builtin_amdgcn_mfma_f32_16x16x32_bf16(
                    af[i], bfr[j], acc[i][j], 0, 0, 0);
    }

    float*  Cf = (float*)Cout;
    __bf16* Cb = (__bf16*)Cout;
    #pragma unroll
    for (int i = 0; i < 4; i++) {
        const int row0 = bm + wy * 64 + i * 16 + quad * 4;
        #pragma unroll
        for (int j = 0; j < JT; j++) {
            const int col = bn + wx * JT * 16 + j * 16 + m16;
            const float bv = bias[col];
            float vv[4];
            #pragma unroll
            for (int r = 0; r < 4; r++) {
                float v = acc[i][j][r] + bv;
                if (RELU) v = fmaxf(v, 0.f);
                vv[r] = v;
                if (OUTBF) Cb[(size_t)(row0 + r) * N + col] = (__bf16)v;
                else       Cf[(size_t)(row0 + r) * N + col] = v;
            }
            if (VW && col >= 1024) {            // V slice -> Vt[b*8+h][d][s]
                const int cc = col - 1024;
                const int bb = row0 >> 10, ss = row0 & 1023;
                bf16x4 pv;
                #pragma unroll
                for (int r = 0; r < 4; r++) pv[r] = (__bf16)vv[r];
                *(bf16x4*)&Vt[((size_t)(bb * Hn + (cc >> 6)) * DKn + (cc & 63)) * Sn + ss] = pv;
            }
        }
    }
}

// ---------------------------------------------------------------------------
// MFMA flash attention (causal), software-pipelined, barrier-free k-loop.
// qkv: [M][1536] bf16; Vt: [b*8+h][64][1024] bf16.
// Block = (q-tile 64, h, b) -> 1024 blocks. 4 waves; wave w owns q-rows
// w*16..+15. K fragments for tile kt+1 prefetched into registers while tile
// kt computes; V loads issued at iteration top, consumed after softmax.
// Only LDS: per-wave P scratch (C/D -> A layout round-trip, in-order DS).
// Online softmax in registers via width-16 shfl_xor.
// ---------------------------------------------------------------------------
__device__ __forceinline__ void softmax_update(
    f32x4 sv[4], float m[4], float l[4], f32x4 acc[4],
    bool diag, int wave16, int quad, int m16,
    __bf16 (*Pw)[72], bf16x8& pf0, bf16x8& pf1)
{
    #pragma unroll
    for (int j = 0; j < 4; j++)
        #pragma unroll
        for (int r = 0; r < 4; r++) {
            float v = sv[j][r] * 0.125f;    // 1/sqrt(64)
            if (diag && (j * 16 + m16) > (wave16 + quad * 4 + r)) v = -1e30f;
            sv[j][r] = v;
        }

    float pm[4];
    #pragma unroll
    for (int r = 0; r < 4; r++)
        pm[r] = fmaxf(fmaxf(sv[0][r], sv[1][r]), fmaxf(sv[2][r], sv[3][r]));
    #pragma unroll
    for (int off = 1; off < 16; off <<= 1)
        #pragma unroll
        for (int r = 0; r < 4; r++)
            pm[r] = fmaxf(pm[r], __shfl_xor(pm[r], off, 16));

    float al[4];
    #pragma unroll
    for (int r = 0; r < 4; r++) {
        float mn = fmaxf(m[r], pm[r]);
        al[r] = __expf(m[r] - mn);
        m[r] = mn;
    }

    float rs[4] = {0.f, 0.f, 0.f, 0.f};
    #pragma unroll
    for (int j = 0; j < 4; j++)
        #pragma unroll
        for (int r = 0; r < 4; r++) {
            float p = __expf(sv[j][r] - m[r]);
            rs[r] += p;
            Pw[quad * 4 + r][j * 16 + m16] = (__bf16)p;
        }
    #pragma unroll
    for (int off = 1; off < 16; off <<= 1)
        #pragma unroll
        for (int r = 0; r < 4; r++)
            rs[r] += __shfl_xor(rs[r], off, 16);
    #pragma unroll
    for (int r = 0; r < 4; r++) l[r] = l[r] * al[r] + rs[r];

    #pragma unroll
    for (int j = 0; j < 4; j++)
        #pragma unroll
        for (int r = 0; r < 4; r++) acc[j][r] *= al[r];

    pf0 = *(const bf16x8*)&Pw[m16][quad * 8];
    pf1 = *(const bf16x8*)&Pw[m16][32 + quad * 8];
}

__global__ __launch_bounds__(256) void k_attn_mfma(
    const __bf16* __restrict__ qkv, const __bf16* __restrict__ Vt,
    __bf16* __restrict__ o)
{
    const int qt  = blockIdx.x;          // 0..15
    const int h   = blockIdx.y;
    const int b   = blockIdx.z;
    const int tid  = threadIdx.x;
    const int lane = tid & 63, wave = tid >> 6;
    const int m16  = lane & 15, quad = lane >> 4;
    const int wave16 = wave * 16;
    const int q0   = qt * 64;

    __shared__ __bf16 Ps[4][16][72];     // per-wave P scratch, rows 144B (16B-aligned)

    const __bf16* base = qkv + (size_t)b * Sn * 1536 + h * DKn;   // Q +0, K +512
    const __bf16* vtb  = Vt + (size_t)(b * Hn + h) * DKn * Sn;

    bf16x8 qf0, qf1;
    {
        const __bf16* qrow = base + (size_t)(q0 + wave16 + m16) * 1536 + quad * 8;
        qf0 = *(const bf16x8*)qrow;
        qf1 = *(const bf16x8*)(qrow + 32);
    }

    float mr[4], lr[4];
    f32x4 acc[4];
    #pragma unroll
    for (int r = 0; r < 4; r++) {
        mr[r] = -1e30f; lr[r] = 0.f;
        acc[r] = (f32x4){0.f, 0.f, 0.f, 0.f};
    }

    // per-lane K fragment base: row (kt*64 + j*16 + m16), col 512 + quad*8
    const __bf16* kbase = base + 512 + (size_t)m16 * 1536 + quad * 8;

    // prime: K tile 0
    bf16x8 kc[4][2];
    #pragma unroll
    for (int j = 0; j < 4; j++) {
        const __bf16* kp = kbase + (size_t)(j * 16) * 1536;
        kc[j][0] = *(const bf16x8*)kp;
        kc[j][1] = *(const bf16x8*)(kp + 32);
    }

    for (int kt = 0; kt <= qt; kt++) {
        const int k0 = kt * 64;

        // prefetch next K tile (registers; consumed next iteration)
        bf16x8 kn[4][2];
        if (kt < qt) {
            #pragma unroll
            for (int j = 0; j < 4; j++) {
                const __bf16* kp = kbase + (size_t)(k0 + 64 + j * 16) * 1536;
                kn[j][0] = *(const bf16x8*)kp;
                kn[j][1] = *(const bf16x8*)(kp + 32);
            }
        }
        // V loads for current tile (consumed after softmax — latency hidden)
        bf16x8 vf[4][2];
        #pragma unroll
        for (int jd = 0; jd < 4; jd++) {
            const __bf16* vp = vtb + (size_t)(jd * 16 + m16) * Sn + k0 + quad * 8;
            vf[jd][0] = *(const bf16x8*)vp;
            vf[jd][1] = *(const bf16x8*)(vp + 32);
        }

        // ---- S = Q K^T ----
        f32x4 sv[4];
        #pragma unroll
        for (int j = 0; j < 4; j++) {
            f32x4 s = (f32x4){0.f, 0.f, 0.f, 0.f};
            s = __builtin_amdgcn_mfma_f32_16x16x32_bf16(qf0, kc[j][0], s, 0, 0, 0);
            s = __builtin_amdgcn_mfma_f32_16x16x32_bf16(qf1, kc[j][1], s, 0, 0, 0);
            sv[j] = s;
        }

        // ---- online softmax (per-wave LDS round-trip, in-order DS) ----
        bf16x8 pf0, pf1;
        softmax_update(sv, mr, lr, acc, kt == qt, wave16, quad, m16, Ps[wave], pf0, pf1);

        // ---- O += P V ----
        #pragma unroll
        for (int jd = 0; jd < 4; jd++) {
            acc[jd] = __builtin_amdgcn_mfma_f32_16x16x32_bf16(pf0, vf[jd][0], acc[jd], 0, 0, 0);
            acc[jd] = __builtin_amdgcn_mfma_f32_16x16x32_bf16(pf1, vf[jd][1], acc[jd], 0, 0, 0);
        }

        // rotate prefetched K into current
        if (kt < qt) {
            #pragma unroll
            for (int j = 0; j < 4; j++) { kc[j][0] = kn[j][0]; kc[j][1] = kn[j][1]; }
        }
    }

    // epilogue: O / l
    #pragma unroll
    for (int r = 0; r < 4; r++) lr[r] = 1.0f / lr[r];
    #pragma unroll
    for (int jd = 0; jd < 4; jd++)
        #pragma unroll
        for (int r = 0; r < 4; r++) {
            const int row = b * Sn + q0 + wave16 + quad * 4 + r;
            o[(size_t)row * Dn + h * DKn + jd * 16 + m16] = (__bf16)(acc[jd][r] * lr[r]);
        }
}

// ---------------------------------------------------------------------------
// x = LayerNorm(t + x); writes fp32 x and bf16 copy xb.
// ---------------------------------------------------------------------------
__device__ inline float block_reduce_sum(float v, float* red, int tid) {
    red[tid] = v;
    __syncthreads();
    for (int s = 128; s > 0; s >>= 1) {
        if (tid < s) red[tid] += red[tid + s];
        __syncthreads();
    }
    float r = red[0];
    __syncthreads();
    return r;
}

__global__ __launch_bounds__(256) void k_residual_ln(
    const float* __restrict__ t, float* __restrict__ x, __bf16* __restrict__ xb,
    const float* __restrict__ g, const float* __restrict__ be)
{
    __shared__ float red[256];
    const int row = blockIdx.x, tid = threadIdx.x;
    const size_t base = (size_t)row * Dn;

    float v0 = t[base + tid] + x[base + tid];
    float v1 = t[base + 256 + tid] + x[base + 256 + tid];

    float mean = block_reduce_sum(v0 + v1, red, tid) * (1.0f / Dn);
    float d0 = v0 - mean, d1 = v1 - mean;
    float var = block_reduce_sum(d0 * d0 + d1 * d1, red, tid) * (1.0f / Dn);
    float inv = rsqrtf(var + 1e-5f);

    float o0 = d0 * inv * g[tid]       + be[tid];
    float o1 = d1 * inv * g[256 + tid] + be[256 + tid];
    x[base + tid]        = o0;
    x[base + 256 + tid]  = o1;
    xb[base + tid]       = (__bf16)o0;
    xb[base + 256 + tid] = (__bf16)o1;
}

// ---------------------------------------------------------------------------
// launcher
// ---------------------------------------------------------------------------
extern "C" void kernel_launch(void* const* d_in, const int* in_sizes, int n_in,
                              void* d_out, int out_size, void* d_ws, size_t ws_size,
                              hipStream_t stream)
{
    const float* x_in   = (const float*)d_in[0];
    const float* qkv_w  = (const float*)d_in[1];
    const float* qkv_b  = (const float*)d_in[2];
    const float* out_w  = (const float*)d_in[3];
    const float* out_b  = (const float*)d_in[4];
    const float* ln1_g  = (const float*)d_in[5];
    const float* ln1_b  = (const float*)d_in[6];
    const float* mlp_w1 = (const float*)d_in[7];
    const float* mlp_b1 = (const float*)d_in[8];
    const float* mlp_w2 = (const float*)d_in[9];
    const float* mlp_b2 = (const float*)d_in[10];
    const float* ln2_g  = (const float*)d_in[11];
    const float* ln2_b  = (const float*)d_in[12];

    // workspace layout (~94 MB)
    char* p = (char*)d_ws;
    float*  X    = (float*)p;  p += (size_t)Mn * Dn * 4;        // 16 MB fp32 residual
    __bf16* Xb   = (__bf16*)p; p += (size_t)Mn * Dn * 2;        //  8 MB bf16 x
    __bf16* QKVb = (__bf16*)p; p += (size_t)Mn * 3 * Dn * 2;    // 24 MB
    __bf16* AOb  = (__bf16*)p; p += (size_t)Mn * Dn * 2;        //  8 MB attn out
    __bf16* Hb   = (__bf16*)p; p += (size_t)Mn * DFFn * 2;      // 32 MB mlp hidden
    __bf16* Wq   = (__bf16*)p; p += (size_t)3 * Dn * Dn * 2;    // 1.5 MB  [1536][512]
    __bf16* Wo   = (__bf16*)p; p += (size_t)Dn * Dn * 2;        // 0.5 MB  [512][512]
    __bf16* W1   = (__bf16*)p; p += (size_t)DFFn * Dn * 2;      // 2 MB    [2048][512]
    __bf16* W2   = (__bf16*)p; p += (size_t)Dn * DFFn * 2;      // 2 MB    [512][2048]
    __bf16* Vt   = Hb;             // 8 MB, aliased: Hb dead during attention
    float* BUF3 = (float*)d_out;   // pre-LN temp lives in d_out

    const size_t xBytes = (size_t)Mn * Dn * sizeof(float);
    hipMemcpyAsync(X, x_in, xBytes, hipMemcpyDeviceToDevice, stream);
    k_cast_bf16<<<(Mn * Dn) / 256, 256, 0, stream>>>(x_in, Xb, Mn * Dn);

    for (int l = 0; l < Ln; l++) {
        // all 4 weight transposes in one launch
        k_trans_all<<<3072, dim3(32, 8), 0, stream>>>(
            qkv_w + (size_t)l * Dn * 3 * Dn, out_w + (size_t)l * Dn * Dn,
            mlp_w1 + (size_t)l * Dn * DFFn, mlp_w2 + (size_t)l * DFFn * Dn,
            Wq, Wo, W1, W2);

        // QKV projection -> bf16 [M,1536] + fused Vt scatter
        k_gemm_mfma<0, 1, 4, 1><<<dim3(12, 64), 256, 0, stream>>>(
            Xb, Wq, qkv_b + (size_t)l * 3 * Dn, QKVb, Vt, Mn, 3 * Dn, Dn);
        // pipelined MFMA flash attention -> bf16 [M,512]
        k_attn_mfma<<<dim3(16, Hn, Bn), 256, 0, stream>>>(QKVb, Vt, AOb);
        // output projection -> fp32 BUF3
        k_gemm_mfma<0, 0, 2, 0><<<dim3(8, 64), 256, 0, stream>>>(
            AOb, Wo, out_b + (size_t)l * Dn, BUF3, nullptr, Mn, Dn, Dn);
        // x = LN(proj + x)
        k_residual_ln<<<Mn, 256, 0, stream>>>(BUF3, X, Xb,
            ln1_g + (size_t)l * Dn, ln1_b + (size_t)l * Dn);
        // MLP up + ReLU -> bf16 [M,2048]  (overwrites Vt alias; attn done)
        k_gemm_mfma<1, 1, 4, 0><<<dim3(16, 64), 256, 0, stream>>>(
            Xb, W1, mlp_b1 + (size_t)l * DFFn, Hb, nullptr, Mn, DFFn, Dn);
        // MLP down -> fp32 BUF3
        k_gemm_mfma<0, 0, 2, 0><<<dim3(8, 64), 256, 0, stream>>>(
            Hb, W2, mlp_b2 + (size_t)l * Dn, BUF3, nullptr, Mn, Dn, DFFn);
        // x = LN(x + mlp)
        k_residual_ln<<<Mn, 256, 0, stream>>>(BUF3, X, Xb,
            ln2_g + (size_t)l * Dn, ln2_b + (size_t)l * Dn);
    }

    hipMemcpyAsync(d_out, X, xBytes, hipMemcpyDeviceToDevice, stream);
}